// Round 10
// baseline (236.658 us; speedup 1.0000x reference)
//
#include <hip/hip_runtime.h>
#include <math.h>

// ---------------------------------------------------------------------------
// RecursiveEncoder forward, fp16 MFMA pipeline. Round 12:
//  = Round-9 config (219.6 us; k2 coalesced-epilogue verified: dropped out of
//    top-5) with k1 RESTRUCTURED for occupancy:
//  - k1: 512 threads / 8 waves per block, each wave owns N=32 (nt=2).
//    Per-thread state halves (acc 40 AGPR, bs 24 VGPR, peak ~105 combined)
//    -> __launch_bounds__(512,4) (VGPR cap 128, ~20% margin — unlike the
//    poisoned (256,3) configs at demand~=cap). LDS unchanged -> 2 blocks/CU,
//    but waves/SIMD DOUBLES 2->4. r9 counters showed k1 latency-bound:
//    MfmaUtil 38 / VALU 48 / occ 26, ~75% dependent-chain stall.
//  - k2 / kconv byte-identical to round 9.
// ---------------------------------------------------------------------------

#define NPAR  32768
#define LDA1  328        // k1 activation row (halfs): K=320 + 8 pad
#define LDA2  264        // xbuf row (halfs): K=256 + 8 pad
// ws layout (halfs):
#define W1F_OFF   0                  // frag-order W1^T: ((n16*10+c)*64+lane)*8
#define W2F_OFF   81920              // 4 x frag-order [((n16*8+c)*64+lane)*8]
#define WBX_OFF   (81920 + 4*65536)  // frag-order Wbox^T: ((n16*64+lane))*8
#define XBUF_OFF  (WBX_OFF + 8192)   // = 352256; [NPAR][264]

typedef _Float16 f16;
typedef _Float16 f16x8 __attribute__((ext_vector_type(8)));
typedef float    f32x4 __attribute__((ext_vector_type(4)));

__device__ __forceinline__ void async16(const void* g, void* l) {
    __builtin_amdgcn_global_load_lds((const __attribute__((address_space(1))) void*)g,
                                     (__attribute__((address_space(3))) void*)l, 16, 0, 0);
}
__device__ __forceinline__ f32x4 mfma16(f16x8 a, f16x8 b, f32x4 c) {
    return __builtin_amdgcn_mfma_f32_16x16x32_f16(a, b, c, 0, 0, 0);
}

// ---------------- kconv: fragment-ordered f16 weights ------------------------
// Fragment layout: for col-tile n16 (16 cols), k-chunk c (32 k), lane=q*16+r16
// holds halfs j=0..7 of W^T[n16*16+r16][c*32+q*8+j]  (= W[k][n]).
__global__ void kconv(const float* __restrict__ W1, const float* __restrict__ W2,
                      const float* __restrict__ Ws1, const float* __restrict__ Wmu,
                      const float* __restrict__ Wvar, const float* __restrict__ Wbox,
                      f16* __restrict__ ws) {
    int idx = blockIdx.x * 256 + threadIdx.x;
    if (idx < 81920) {                       // W1F (K=320: 10 chunks)
        int j = idx & 7, lane = (idx >> 3) & 63, t = idx >> 9;   // t = n16*10+c
        int c = t % 10, n16 = t / 10;
        int k = c * 32 + (lane >> 4) * 8 + j;
        int n = n16 * 16 + (lane & 15);
        ws[idx] = (f16)W1[k * 256 + n];
    } else if (idx < WBX_OFF) {              // W2/Ws1/Wmu/Wvar (K=256: 8 chunks)
        int r = idx - 81920;
        int wsel = r >> 16, r2 = r & 65535;
        const float* s = (wsel == 0) ? W2 : (wsel == 1) ? Ws1 : (wsel == 2) ? Wmu : Wvar;
        int j = r2 & 7, lane = (r2 >> 3) & 63, c = (r2 >> 9) & 7, n16 = r2 >> 12;
        int k = c * 32 + (lane >> 4) * 8 + j;
        int n = n16 * 16 + (lane & 15);
        ws[idx] = (f16)s[k * 256 + n];
    } else if (idx < XBUF_OFF) {             // WboxF (K=32 zero-padded, 1 chunk)
        int r = idx - WBX_OFF;
        int j = r & 7, lane = (r >> 3) & 63, n16 = r >> 9;
        int k = (lane >> 4) * 8 + j;
        int n = n16 * 16 + (lane & 15);
        ws[idx] = (f16)((k < 10) ? Wbox[k * 256 + n] : 0.f);
    }
}

// ---------------- k1: leaf MFMA + K=320 GEMM (one-hot fused) + reg max-pool --
// block = 8 parents = 80 rows; grid 4096; 512 thr (8 waves, each N=32)
// Row PERMUTATION: child (p,m) lives at lA row d = m*8 + p. Then C row
// mt*16+q*4+i has p = i+4*(q&1), m = 2*mt+(q>>1)  (all compile-time indices).
__global__ __launch_bounds__(512, 4)
void k1(const float* __restrict__ box, const float* __restrict__ bbox,
        const float* __restrict__ b1, const int* __restrict__ sem,
        const int* __restrict__ nch, const f16* __restrict__ wsh,
        f16* __restrict__ xbuf) {
    __shared__ __align__(16) f16 lA[80 * LDA1];   // 52480 B
    __shared__ int lnc[8];

    int tid = threadIdx.x, blk = blockIdx.x;
    int w = tid >> 6, lane = tid & 63, q = lane >> 4, r16 = lane & 15;
    const f16* w1f = wsh + W1F_OFF;
    const f16* wbxf = wsh + WBX_OFF;

    if (tid < 8) lnc[tid] = nch[blk * 8 + tid];

    float bbv[2], b1v[2];
    #pragma unroll
    for (int nt = 0; nt < 2; nt++) {
        int col = w * 32 + nt * 16 + r16;
        bbv[nt] = bbox[col];
        b1v[nt] = b1[col];
    }

    // ---- leaf: relu(box @ Wbox + bbox), K=32 zero-padded, coalesced frags
    f32x4 acc[5][2];
    {
        f16x8 bb[2], ab[5];
        #pragma unroll
        for (int nt = 0; nt < 2; nt++)
            bb[nt] = *(const f16x8*)&wbxf[((w * 2 + nt) * 64 + lane) * 8];
        #pragma unroll
        for (int mt = 0; mt < 5; mt++) {
            const float* bp = box + (size_t)blk * 800 + (mt * 16 + r16) * 10;
            float v[8] = {0.f, 0.f, 0.f, 0.f, 0.f, 0.f, 0.f, 0.f};
            if (q == 0) {
                float2 t0 = *(const float2*)(bp + 0), t1 = *(const float2*)(bp + 2);
                float2 t2 = *(const float2*)(bp + 4), t3 = *(const float2*)(bp + 6);
                v[0] = t0.x; v[1] = t0.y; v[2] = t1.x; v[3] = t1.y;
                v[4] = t2.x; v[5] = t2.y; v[6] = t3.x; v[7] = t3.y;
            } else if (q == 1) {
                float2 t = *(const float2*)(bp + 8);
                v[0] = t.x; v[1] = t.y;
            }
            f16x8 t;
            #pragma unroll
            for (int j = 0; j < 8; j++) t[j] = (f16)v[j];
            ab[mt] = t;
        }
        #pragma unroll
        for (int mt = 0; mt < 5; mt++)
            #pragma unroll
            for (int nt = 0; nt < 2; nt++)
                acc[mt][nt] = mfma16(ab[mt], bb[nt], (f32x4){0.f, 0.f, 0.f, 0.f});
    }
    // leaf -> lA (C-layout scatter, PERMUTED rows d = m*8+p)
    #pragma unroll
    for (int mt = 0; mt < 5; mt++) {
        #pragma unroll
        for (int i = 0; i < 4; i++) {
            int r = mt * 16 + q * 4 + i;        // original child row 0..79
            int p = (r * 205) >> 11;            // r / 10 (exact for r<80)
            int d = (r - 10 * p) * 8 + p;       // permuted row
            #pragma unroll
            for (int nt = 0; nt < 2; nt++) {
                int col = w * 32 + nt * 16 + r16;
                lA[d * LDA1 + col] = (f16)fmaxf(acc[mt][nt][i] + bbv[nt], 0.f);
            }
        }
    }
    // one-hot region k=256..319: tid IS the permuted row d (p=d&7, m=d>>3)
    if (tid < 80) {
        int p8 = tid & 7, m8 = tid >> 3;
        int sid = sem[blk * 80 + p8 * 10 + m8];
        f16x8 z = {(f16)0.f, (f16)0.f, (f16)0.f, (f16)0.f, (f16)0.f, (f16)0.f, (f16)0.f, (f16)0.f};
        #pragma unroll
        for (int j = 0; j < 8; j++) *(f16x8*)&lA[tid * LDA1 + 256 + j * 8] = z;
        lA[tid * LDA1 + 256 + sid] = (f16)1.f;
    }

    // ---- main GEMM: K=320, coalesced frag stream, 3-deep pipeline
    #pragma unroll
    for (int mt = 0; mt < 5; mt++)
        #pragma unroll
        for (int nt = 0; nt < 2; nt++) acc[mt][nt] = (f32x4){0.f, 0.f, 0.f, 0.f};

    f16x8 bs[3][2];
    auto loadB = [&](int c, int s) {
        #pragma unroll
        for (int nt = 0; nt < 2; nt++)
            bs[s][nt] = *(const f16x8*)&w1f[(((w * 2 + nt) * 10 + c) * 64 + lane) * 8];
    };
    loadB(0, 0); loadB(1, 1); loadB(2, 2);
    __syncthreads();                               // lA (leaf + one-hot) visible
    #pragma unroll
    for (int c = 0; c < 10; c++) {
        f16x8 a[5];
        #pragma unroll
        for (int mt = 0; mt < 5; mt++)
            a[mt] = *(const f16x8*)&lA[(mt * 16 + r16) * LDA1 + c * 32 + q * 8];
        int s = c % 3;
        #pragma unroll
        for (int mt = 0; mt < 5; mt++)
            #pragma unroll
            for (int nt = 0; nt < 2; nt++) acc[mt][nt] = mfma16(a[mt], bs[s][nt], acc[mt][nt]);
        if (c + 3 < 10) loadB(c + 3, s);
    }
    // NO barrier: lA never rewritten; epilogue is all in registers.

    // ---- in-register masked max-pool over children
    int qh = q >> 1, qb = q & 1;
    int ncv[4];
    #pragma unroll
    for (int i = 0; i < 4; i++) ncv[i] = lnc[4 * qb + i];   // parent p = i + 4*qb
    float pm[4][2];
    #pragma unroll
    for (int i = 0; i < 4; i++)
        #pragma unroll
        for (int nt = 0; nt < 2; nt++) pm[i][nt] = 0.f;
    #pragma unroll
    for (int mt = 0; mt < 5; mt++) {
        int m = 2 * mt + qh;                                 // child index
        #pragma unroll
        for (int i = 0; i < 4; i++) {
            bool live = m < ncv[i];
            #pragma unroll
            for (int nt = 0; nt < 2; nt++) {
                float v = fmaxf(acc[mt][nt][i] + b1v[nt], 0.f);
                pm[i][nt] = fmaxf(pm[i][nt], live ? v : 0.f);
            }
        }
    }
    // combine even-m partials (q=0,1) with odd-m partials (q=2,3): lane ^ 32
    #pragma unroll
    for (int i = 0; i < 4; i++)
        #pragma unroll
        for (int nt = 0; nt < 2; nt++)
            pm[i][nt] = fmaxf(pm[i][nt], __shfl_xor(pm[i][nt], 32, 64));
    // q=0 writes parents 0..3, q=1 writes parents 4..7 (q=2,3 hold duplicates)
    if (q < 2) {
        #pragma unroll
        for (int i = 0; i < 4; i++) {
            size_t row = (size_t)blk * 8 + 4 * q + i;
            #pragma unroll
            for (int nt = 0; nt < 2; nt++)
                xbuf[row * LDA2 + w * 32 + nt * 16 + r16] = (f16)pm[i][nt];
        }
    }
}

// ---------------- k2: sampler chain, M=32/block, coalesced epilogue ----------
// grid 1024; 256 thr; LDS = 33792 B (actA | actB, reused as f32 transpose buf)
// Epilogue: mu/lv round-trip through LDS f32 [16][260] halves (stride 260:
// write banks 2-way free, reads contiguous), then f32x4 eps loads and f32x4
// out stores — 1KB per wave-inst, no partial-line HBM writes.
__global__ __launch_bounds__(256, 3)
void k2(const f16* __restrict__ xbuf, const f16* __restrict__ wsh,
        const float* __restrict__ b2, const float* __restrict__ bs1,
        const float* __restrict__ bmu, const float* __restrict__ bvar,
        const float* __restrict__ eps, float* __restrict__ out) {
    __shared__ __align__(16) f16 sh[2 * 32 * LDA2];   // 33792 B
    f16* actA = sh;
    f16* actB = sh + 32 * LDA2;
    float* sh32 = (float*)sh;                         // epilogue transpose buf
    const int LVW = 16 * 260;                         // lv f32-word offset

    int tid = threadIdx.x, blk = blockIdx.x;
    int w = tid >> 6, lane = tid & 63, q = lane >> 4, r16 = lane & 15;
    const f16* w2f   = wsh + W2F_OFF;
    const f16* ws1f  = w2f + 65536;
    const f16* wmuf  = w2f + 2 * 65536;
    const f16* wvarf = w2f + 3 * 65536;

    float b2v[4], bs1v[4], bmv[4], bvv[4];
    #pragma unroll
    for (int nt = 0; nt < 4; nt++) {
        int col = w * 64 + nt * 16 + r16;
        b2v[nt] = b2[col]; bs1v[nt] = bs1[col];
        bmv[nt] = bmu[col]; bvv[nt] = bvar[col];
    }

    {   // stage x tile (16896 B flat) -> actA
        const char* src = (const char*)(xbuf + (size_t)blk * 32 * LDA2);
        #pragma unroll
        for (int j = 0; j < 5; j++) {
            int idx = tid + j * 256;
            if (idx < 1056) async16(src + idx * 16, (char*)actA + idx * 16);
        }
    }

    f32x4 acc[2][4];
    f16x8 bs[3][4];
    auto loadB = [&](const f16* wt, int c, int s) {
        #pragma unroll
        for (int nt = 0; nt < 4; nt++)
            bs[s][nt] = *(const f16x8*)&wt[(((w * 4 + nt) * 8 + c) * 64 + lane) * 8];
    };
    auto gemm = [&](const f16* A, const f16* wt) {   // caller preloads bs[0..2]
        #pragma unroll
        for (int mt = 0; mt < 2; mt++)
            #pragma unroll
            for (int nt = 0; nt < 4; nt++) acc[mt][nt] = (f32x4){0.f, 0.f, 0.f, 0.f};
        #pragma unroll
        for (int c = 0; c < 8; c++) {
            f16x8 a[2];
            #pragma unroll
            for (int mt = 0; mt < 2; mt++)
                a[mt] = *(const f16x8*)&A[(mt * 16 + r16) * LDA2 + c * 32 + q * 8];
            int s = c % 3;
            #pragma unroll
            for (int mt = 0; mt < 2; mt++)
                #pragma unroll
                for (int nt = 0; nt < 4; nt++) acc[mt][nt] = mfma16(a[mt], bs[s][nt], acc[mt][nt]);
            if (c + 3 < 8) loadB(wt, c + 3, s);
        }
    };

    // stage1: parent = relu(x @ W2 + b2) -> actB
    loadB(w2f, 0, 0); loadB(w2f, 1, 1); loadB(w2f, 2, 2);
    __syncthreads();                               // drains actA staging
    gemm(actA, w2f);
    #pragma unroll
    for (int nt = 0; nt < 4; nt++) {
        int col = w * 64 + nt * 16 + r16;
        #pragma unroll
        for (int mt = 0; mt < 2; mt++)
            #pragma unroll
            for (int i = 0; i < 4; i++)
                actB[(mt * 16 + q * 4 + i) * LDA2 + col] = (f16)fmaxf(acc[mt][nt][i] + b2v[nt], 0.f);
    }
    loadB(ws1f, 0, 0); loadB(ws1f, 1, 1); loadB(ws1f, 2, 2);
    __syncthreads();

    // stage2: enc = relu(parent @ Ws1 + bs1) -> actA
    gemm(actB, ws1f);
    #pragma unroll
    for (int nt = 0; nt < 4; nt++) {
        int col = w * 64 + nt * 16 + r16;
        #pragma unroll
        for (int mt = 0; mt < 2; mt++)
            #pragma unroll
            for (int i = 0; i < 4; i++)
                actA[(mt * 16 + q * 4 + i) * LDA2 + col] = (f16)fmaxf(acc[mt][nt][i] + bs1v[nt], 0.f);
    }
    loadB(wmuf, 0, 0); loadB(wmuf, 1, 1); loadB(wmuf, 2, 2);
    __syncthreads();

    // stage3: mu -> regs
    gemm(actA, wmuf);
    f32x4 mu[2][4];
    #pragma unroll
    for (int mt = 0; mt < 2; mt++)
        #pragma unroll
        for (int nt = 0; nt < 4; nt++) mu[mt][nt] = acc[mt][nt];

    // stage4: logvar (actA unchanged since stage2 write: no barrier needed)
    loadB(wvarf, 0, 0); loadB(wvarf, 1, 1); loadB(wvarf, 2, 2);
    gemm(actA, wvarf);
    __syncthreads();       // all waves done reading actA; sh reusable as f32 buf

    // ---- coalesced epilogue: two 16-row halves through LDS ----
    #pragma unroll
    for (int h = 0; h < 2; h++) {
        if (h) __syncthreads();                    // previous half's reads done
        // transpose-in: this thread's mt==h slice (rows h*16 + q*4+i)
        #pragma unroll
        for (int nt = 0; nt < 4; nt++) {
            int col = w * 64 + nt * 16 + r16;
            #pragma unroll
            for (int i = 0; i < 4; i++) {
                int row16 = q * 4 + i;
                sh32[row16 * 260 + col]       = mu[h][nt][i] + bmv[nt];
                sh32[LVW + row16 * 260 + col] = acc[h][nt][i] + bvv[nt];
            }
        }
        __syncthreads();
        // whole-row f32x4 phase: wave w covers rows 4j+w, lanes span 256 cols
        #pragma unroll
        for (int j = 0; j < 4; j++) {
            int row16 = 4 * j + w;
            size_t grow = (size_t)blk * 32 + h * 16 + row16;
            f32x4 m4 = *(const f32x4*)&sh32[row16 * 260 + lane * 4];
            f32x4 l4 = *(const f32x4*)&sh32[LVW + row16 * 260 + lane * 4];
            f32x4 e4 = *(const f32x4*)&eps[grow * 256 + lane * 4];
            f32x4 o1, o2;
            #pragma unroll
            for (int i = 0; i < 4; i++) {
                float e = expf(l4[i]);
                o1[i] = e4[i] * sqrtf(e) + m4[i];
                o2[i] = 1.f + l4[i] - m4[i] * m4[i] - e;
            }
            *(f32x4*)&out[grow * 512 + lane * 4]       = o1;
            *(f32x4*)&out[grow * 512 + 256 + lane * 4] = o2;
        }
    }
}

// ---------------------------------------------------------------------------
extern "C" void kernel_launch(void* const* d_in, const int* in_sizes, int n_in,
                              void* d_out, int out_size, void* d_ws, size_t ws_size,
                              hipStream_t stream) {
    const float* box  = (const float*)d_in[0];
    const float* eps  = (const float*)d_in[1];
    const float* Wbox = (const float*)d_in[2];
    const float* bbox = (const float*)d_in[3];
    const float* W1   = (const float*)d_in[4];
    const float* b1   = (const float*)d_in[5];
    const float* W2   = (const float*)d_in[6];
    const float* b2   = (const float*)d_in[7];
    const float* Ws1  = (const float*)d_in[8];
    const float* bs1  = (const float*)d_in[9];
    const float* Wmu  = (const float*)d_in[10];
    const float* bmu  = (const float*)d_in[11];
    const float* Wvar = (const float*)d_in[12];
    const float* bvar = (const float*)d_in[13];
    const int*   sem  = (const int*)d_in[14];
    const int*   nch  = (const int*)d_in[15];

    f16* wsh  = (f16*)d_ws;
    f16* xbuf = wsh + XBUF_OFF;

    kconv<<<XBUF_OFF / 256, 256, 0, stream>>>(W1, W2, Ws1, Wmu, Wvar, Wbox, wsh);
    k1<<<NPAR / 8, 512, 0, stream>>>(box, bbox, b1, sem, nch, wsh, xbuf);
    k2<<<NPAR / 32, 256, 0, stream>>>(xbuf, wsh, b2, bs1, bmu, bvar, eps, (float*)d_out);
}

// Round 11
// 227.586 us; speedup vs baseline: 1.0399x; 1.0399x over previous
//
#include <hip/hip_runtime.h>
#include <math.h>

// ---------------------------------------------------------------------------
// RecursiveEncoder forward, fp16 MFMA pipeline. Round 13:
//  = Round-9 config (best: 219.6 us) with ONE change: k2 launch_bounds
//    (256,3) -> (256,4).
//  - k2 regs = 84 VGPR + 32 AGPR = 116, inside the 65-128 bracket ->
//    16 waves/CU possible; LDS 33.8KB x 4 = 135KB fits. Cap 128 vs demand
//    116 leaves real margin (unlike the poisoned demand~=cap configs).
//  - k1 REVERTED byte-identical to round-9 (65.5 us). Round-12's 8-wave
//    N-split regressed (90 us): every wave reads the full A-tile -> 2x LDS
//    traffic, conflicts 5.9M->9.2M, MfmaUtil 38->27. k1 is register-bracket
//    bound (164 regs -> 8 waves/CU); all attempts to leave the bracket cost
//    more than they gained. k1's round-9 form is the structural optimum.
// ---------------------------------------------------------------------------

#define NPAR  32768
#define LDA1  328        // k1 activation row (halfs): K=320 + 8 pad
#define LDA2  264        // xbuf row (halfs): K=256 + 8 pad
// ws layout (halfs):
#define W1F_OFF   0                  // frag-order W1^T: ((n16*10+c)*64+lane)*8
#define W2F_OFF   81920              // 4 x frag-order [((n16*8+c)*64+lane)*8]
#define WBX_OFF   (81920 + 4*65536)  // frag-order Wbox^T: ((n16*64+lane))*8
#define XBUF_OFF  (WBX_OFF + 8192)   // = 352256; [NPAR][264]

typedef _Float16 f16;
typedef _Float16 f16x8 __attribute__((ext_vector_type(8)));
typedef float    f32x4 __attribute__((ext_vector_type(4)));

__device__ __forceinline__ void async16(const void* g, void* l) {
    __builtin_amdgcn_global_load_lds((const __attribute__((address_space(1))) void*)g,
                                     (__attribute__((address_space(3))) void*)l, 16, 0, 0);
}
__device__ __forceinline__ f32x4 mfma16(f16x8 a, f16x8 b, f32x4 c) {
    return __builtin_amdgcn_mfma_f32_16x16x32_f16(a, b, c, 0, 0, 0);
}

// ---------------- kconv: fragment-ordered f16 weights ------------------------
// Fragment layout: for col-tile n16 (16 cols), k-chunk c (32 k), lane=q*16+r16
// holds halfs j=0..7 of W^T[n16*16+r16][c*32+q*8+j]  (= W[k][n]).
__global__ void kconv(const float* __restrict__ W1, const float* __restrict__ W2,
                      const float* __restrict__ Ws1, const float* __restrict__ Wmu,
                      const float* __restrict__ Wvar, const float* __restrict__ Wbox,
                      f16* __restrict__ ws) {
    int idx = blockIdx.x * 256 + threadIdx.x;
    if (idx < 81920) {                       // W1F (K=320: 10 chunks)
        int j = idx & 7, lane = (idx >> 3) & 63, t = idx >> 9;   // t = n16*10+c
        int c = t % 10, n16 = t / 10;
        int k = c * 32 + (lane >> 4) * 8 + j;
        int n = n16 * 16 + (lane & 15);
        ws[idx] = (f16)W1[k * 256 + n];
    } else if (idx < WBX_OFF) {              // W2/Ws1/Wmu/Wvar (K=256: 8 chunks)
        int r = idx - 81920;
        int wsel = r >> 16, r2 = r & 65535;
        const float* s = (wsel == 0) ? W2 : (wsel == 1) ? Ws1 : (wsel == 2) ? Wmu : Wvar;
        int j = r2 & 7, lane = (r2 >> 3) & 63, c = (r2 >> 9) & 7, n16 = r2 >> 12;
        int k = c * 32 + (lane >> 4) * 8 + j;
        int n = n16 * 16 + (lane & 15);
        ws[idx] = (f16)s[k * 256 + n];
    } else if (idx < XBUF_OFF) {             // WboxF (K=32 zero-padded, 1 chunk)
        int r = idx - WBX_OFF;
        int j = r & 7, lane = (r >> 3) & 63, n16 = r >> 9;
        int k = (lane >> 4) * 8 + j;
        int n = n16 * 16 + (lane & 15);
        ws[idx] = (f16)((k < 10) ? Wbox[k * 256 + n] : 0.f);
    }
}

// ---------------- k1: leaf MFMA + K=320 GEMM (one-hot fused) + reg max-pool --
// block = 8 parents = 80 rows; grid 4096; 256 thr (4 waves, each N=64)
// Row PERMUTATION: child (p,m) lives at lA row d = m*8 + p. Then C row
// mt*16+q*4+i has p = i+4*(q&1), m = 2*mt+(q>>1)  (all compile-time indices).
__global__ __launch_bounds__(256, 2)
void k1(const float* __restrict__ box, const float* __restrict__ bbox,
        const float* __restrict__ b1, const int* __restrict__ sem,
        const int* __restrict__ nch, const f16* __restrict__ wsh,
        f16* __restrict__ xbuf) {
    __shared__ __align__(16) f16 lA[80 * LDA1];   // 52480 B
    __shared__ int lnc[8];

    int tid = threadIdx.x, blk = blockIdx.x;
    int w = tid >> 6, lane = tid & 63, q = lane >> 4, r16 = lane & 15;
    const f16* w1f = wsh + W1F_OFF;
    const f16* wbxf = wsh + WBX_OFF;

    if (tid < 8) lnc[tid] = nch[blk * 8 + tid];

    float bbv[4], b1v[4];
    #pragma unroll
    for (int nt = 0; nt < 4; nt++) {
        int col = w * 64 + nt * 16 + r16;
        bbv[nt] = bbox[col];
        b1v[nt] = b1[col];
    }

    // ---- leaf: relu(box @ Wbox + bbox), K=32 zero-padded, coalesced frags
    f32x4 acc[5][4];
    {
        f16x8 bb[4], ab[5];
        #pragma unroll
        for (int nt = 0; nt < 4; nt++)
            bb[nt] = *(const f16x8*)&wbxf[((w * 4 + nt) * 64 + lane) * 8];
        #pragma unroll
        for (int mt = 0; mt < 5; mt++) {
            const float* bp = box + (size_t)blk * 800 + (mt * 16 + r16) * 10;
            float v[8] = {0.f, 0.f, 0.f, 0.f, 0.f, 0.f, 0.f, 0.f};
            if (q == 0) {
                float2 t0 = *(const float2*)(bp + 0), t1 = *(const float2*)(bp + 2);
                float2 t2 = *(const float2*)(bp + 4), t3 = *(const float2*)(bp + 6);
                v[0] = t0.x; v[1] = t0.y; v[2] = t1.x; v[3] = t1.y;
                v[4] = t2.x; v[5] = t2.y; v[6] = t3.x; v[7] = t3.y;
            } else if (q == 1) {
                float2 t = *(const float2*)(bp + 8);
                v[0] = t.x; v[1] = t.y;
            }
            f16x8 t;
            #pragma unroll
            for (int j = 0; j < 8; j++) t[j] = (f16)v[j];
            ab[mt] = t;
        }
        #pragma unroll
        for (int mt = 0; mt < 5; mt++)
            #pragma unroll
            for (int nt = 0; nt < 4; nt++)
                acc[mt][nt] = mfma16(ab[mt], bb[nt], (f32x4){0.f, 0.f, 0.f, 0.f});
    }
    // leaf -> lA (C-layout scatter, PERMUTED rows d = m*8+p)
    #pragma unroll
    for (int mt = 0; mt < 5; mt++) {
        #pragma unroll
        for (int i = 0; i < 4; i++) {
            int r = mt * 16 + q * 4 + i;        // original child row 0..79
            int p = (r * 205) >> 11;            // r / 10 (exact for r<80)
            int d = (r - 10 * p) * 8 + p;       // permuted row
            #pragma unroll
            for (int nt = 0; nt < 4; nt++) {
                int col = w * 64 + nt * 16 + r16;
                lA[d * LDA1 + col] = (f16)fmaxf(acc[mt][nt][i] + bbv[nt], 0.f);
            }
        }
    }
    // one-hot region k=256..319: tid IS the permuted row d (p=d&7, m=d>>3)
    if (tid < 80) {
        int p8 = tid & 7, m8 = tid >> 3;
        int sid = sem[blk * 80 + p8 * 10 + m8];
        f16x8 z = {(f16)0.f, (f16)0.f, (f16)0.f, (f16)0.f, (f16)0.f, (f16)0.f, (f16)0.f, (f16)0.f};
        #pragma unroll
        for (int j = 0; j < 8; j++) *(f16x8*)&lA[tid * LDA1 + 256 + j * 8] = z;
        lA[tid * LDA1 + 256 + sid] = (f16)1.f;
    }

    // ---- main GEMM: K=320, coalesced frag stream, 3-deep pipeline
    #pragma unroll
    for (int mt = 0; mt < 5; mt++)
        #pragma unroll
        for (int nt = 0; nt < 4; nt++) acc[mt][nt] = (f32x4){0.f, 0.f, 0.f, 0.f};

    f16x8 bs[3][4];
    auto loadB = [&](int c, int s) {
        #pragma unroll
        for (int nt = 0; nt < 4; nt++)
            bs[s][nt] = *(const f16x8*)&w1f[(((w * 4 + nt) * 10 + c) * 64 + lane) * 8];
    };
    loadB(0, 0); loadB(1, 1); loadB(2, 2);
    __syncthreads();                               // lA (leaf + one-hot) visible
    #pragma unroll
    for (int c = 0; c < 10; c++) {
        f16x8 a[5];
        #pragma unroll
        for (int mt = 0; mt < 5; mt++)
            a[mt] = *(const f16x8*)&lA[(mt * 16 + r16) * LDA1 + c * 32 + q * 8];
        int s = c % 3;
        #pragma unroll
        for (int mt = 0; mt < 5; mt++)
            #pragma unroll
            for (int nt = 0; nt < 4; nt++) acc[mt][nt] = mfma16(a[mt], bs[s][nt], acc[mt][nt]);
        if (c + 3 < 10) loadB(c + 3, s);
    }
    // NO barrier: lA never rewritten; epilogue is all in registers.

    // ---- in-register masked max-pool over children
    int qh = q >> 1, qb = q & 1;
    int ncv[4];
    #pragma unroll
    for (int i = 0; i < 4; i++) ncv[i] = lnc[4 * qb + i];   // parent p = i + 4*qb
    float pm[4][4];
    #pragma unroll
    for (int i = 0; i < 4; i++)
        #pragma unroll
        for (int nt = 0; nt < 4; nt++) pm[i][nt] = 0.f;
    #pragma unroll
    for (int mt = 0; mt < 5; mt++) {
        int m = 2 * mt + qh;                                 // child index
        #pragma unroll
        for (int i = 0; i < 4; i++) {
            bool live = m < ncv[i];
            #pragma unroll
            for (int nt = 0; nt < 4; nt++) {
                float v = fmaxf(acc[mt][nt][i] + b1v[nt], 0.f);
                pm[i][nt] = fmaxf(pm[i][nt], live ? v : 0.f);
            }
        }
    }
    // combine even-m partials (q=0,1) with odd-m partials (q=2,3): lane ^ 32
    #pragma unroll
    for (int i = 0; i < 4; i++)
        #pragma unroll
        for (int nt = 0; nt < 4; nt++)
            pm[i][nt] = fmaxf(pm[i][nt], __shfl_xor(pm[i][nt], 32, 64));
    // q=0 writes parents 0..3, q=1 writes parents 4..7 (q=2,3 hold duplicates)
    if (q < 2) {
        #pragma unroll
        for (int i = 0; i < 4; i++) {
            size_t row = (size_t)blk * 8 + 4 * q + i;
            #pragma unroll
            for (int nt = 0; nt < 4; nt++)
                xbuf[row * LDA2 + w * 64 + nt * 16 + r16] = (f16)pm[i][nt];
        }
    }
}

// ---------------- k2: sampler chain, M=32/block, coalesced epilogue ----------
// grid 1024; 256 thr; LDS = 33792 B; launch_bounds(256,4): regs 116 < 128 cap,
// LDS 33.8KB x 4 = 135KB fits -> 16 waves/CU (was 12).
// Epilogue: mu/lv round-trip through LDS f32 [16][260] halves, then whole-row
// f32x4 eps loads and f32x4 out stores — no partial-line HBM writes.
__global__ __launch_bounds__(256, 4)
void k2(const f16* __restrict__ xbuf, const f16* __restrict__ wsh,
        const float* __restrict__ b2, const float* __restrict__ bs1,
        const float* __restrict__ bmu, const float* __restrict__ bvar,
        const float* __restrict__ eps, float* __restrict__ out) {
    __shared__ __align__(16) f16 sh[2 * 32 * LDA2];   // 33792 B
    f16* actA = sh;
    f16* actB = sh + 32 * LDA2;
    float* sh32 = (float*)sh;                         // epilogue transpose buf
    const int LVW = 16 * 260;                         // lv f32-word offset

    int tid = threadIdx.x, blk = blockIdx.x;
    int w = tid >> 6, lane = tid & 63, q = lane >> 4, r16 = lane & 15;
    const f16* w2f   = wsh + W2F_OFF;
    const f16* ws1f  = w2f + 65536;
    const f16* wmuf  = w2f + 2 * 65536;
    const f16* wvarf = w2f + 3 * 65536;

    float b2v[4], bs1v[4], bmv[4], bvv[4];
    #pragma unroll
    for (int nt = 0; nt < 4; nt++) {
        int col = w * 64 + nt * 16 + r16;
        b2v[nt] = b2[col]; bs1v[nt] = bs1[col];
        bmv[nt] = bmu[col]; bvv[nt] = bvar[col];
    }

    {   // stage x tile (16896 B flat) -> actA
        const char* src = (const char*)(xbuf + (size_t)blk * 32 * LDA2);
        #pragma unroll
        for (int j = 0; j < 5; j++) {
            int idx = tid + j * 256;
            if (idx < 1056) async16(src + idx * 16, (char*)actA + idx * 16);
        }
    }

    f32x4 acc[2][4];
    f16x8 bs[3][4];
    auto loadB = [&](const f16* wt, int c, int s) {
        #pragma unroll
        for (int nt = 0; nt < 4; nt++)
            bs[s][nt] = *(const f16x8*)&wt[(((w * 4 + nt) * 8 + c) * 64 + lane) * 8];
    };
    auto gemm = [&](const f16* A, const f16* wt) {   // caller preloads bs[0..2]
        #pragma unroll
        for (int mt = 0; mt < 2; mt++)
            #pragma unroll
            for (int nt = 0; nt < 4; nt++) acc[mt][nt] = (f32x4){0.f, 0.f, 0.f, 0.f};
        #pragma unroll
        for (int c = 0; c < 8; c++) {
            f16x8 a[2];
            #pragma unroll
            for (int mt = 0; mt < 2; mt++)
                a[mt] = *(const f16x8*)&A[(mt * 16 + r16) * LDA2 + c * 32 + q * 8];
            int s = c % 3;
            #pragma unroll
            for (int mt = 0; mt < 2; mt++)
                #pragma unroll
                for (int nt = 0; nt < 4; nt++) acc[mt][nt] = mfma16(a[mt], bs[s][nt], acc[mt][nt]);
            if (c + 3 < 8) loadB(wt, c + 3, s);
        }
    };

    // stage1: parent = relu(x @ W2 + b2) -> actB
    loadB(w2f, 0, 0); loadB(w2f, 1, 1); loadB(w2f, 2, 2);
    __syncthreads();                               // drains actA staging
    gemm(actA, w2f);
    #pragma unroll
    for (int nt = 0; nt < 4; nt++) {
        int col = w * 64 + nt * 16 + r16;
        #pragma unroll
        for (int mt = 0; mt < 2; mt++)
            #pragma unroll
            for (int i = 0; i < 4; i++)
                actB[(mt * 16 + q * 4 + i) * LDA2 + col] = (f16)fmaxf(acc[mt][nt][i] + b2v[nt], 0.f);
    }
    loadB(ws1f, 0, 0); loadB(ws1f, 1, 1); loadB(ws1f, 2, 2);
    __syncthreads();

    // stage2: enc = relu(parent @ Ws1 + bs1) -> actA
    gemm(actB, ws1f);
    #pragma unroll
    for (int nt = 0; nt < 4; nt++) {
        int col = w * 64 + nt * 16 + r16;
        #pragma unroll
        for (int mt = 0; mt < 2; mt++)
            #pragma unroll
            for (int i = 0; i < 4; i++)
                actA[(mt * 16 + q * 4 + i) * LDA2 + col] = (f16)fmaxf(acc[mt][nt][i] + bs1v[nt], 0.f);
    }
    loadB(wmuf, 0, 0); loadB(wmuf, 1, 1); loadB(wmuf, 2, 2);
    __syncthreads();

    // stage3: mu -> regs
    gemm(actA, wmuf);
    f32x4 mu[2][4];
    #pragma unroll
    for (int mt = 0; mt < 2; mt++)
        #pragma unroll
        for (int nt = 0; nt < 4; nt++) mu[mt][nt] = acc[mt][nt];

    // stage4: logvar (actA unchanged since stage2 write: no barrier needed)
    loadB(wvarf, 0, 0); loadB(wvarf, 1, 1); loadB(wvarf, 2, 2);
    gemm(actA, wvarf);
    __syncthreads();       // all waves done reading actA; sh reusable as f32 buf

    // ---- coalesced epilogue: two 16-row halves through LDS ----
    #pragma unroll
    for (int h = 0; h < 2; h++) {
        if (h) __syncthreads();                    // previous half's reads done
        // transpose-in: this thread's mt==h slice (rows h*16 + q*4+i)
        #pragma unroll
        for (int nt = 0; nt < 4; nt++) {
            int col = w * 64 + nt * 16 + r16;
            #pragma unroll
            for (int i = 0; i < 4; i++) {
                int row16 = q * 4 + i;
                sh32[row16 * 260 + col]       = mu[h][nt][i] + bmv[nt];
                sh32[LVW + row16 * 260 + col] = acc[h][nt][i] + bvv[nt];
            }
        }
        __syncthreads();
        // whole-row f32x4 phase: wave w covers rows 4j+w, lanes span 256 cols
        #pragma unroll
        for (int j = 0; j < 4; j++) {
            int row16 = 4 * j + w;
            size_t grow = (size_t)blk * 32 + h * 16 + row16;
            f32x4 m4 = *(const f32x4*)&sh32[row16 * 260 + lane * 4];
            f32x4 l4 = *(const f32x4*)&sh32[LVW + row16 * 260 + lane * 4];
            f32x4 e4 = *(const f32x4*)&eps[grow * 256 + lane * 4];
            f32x4 o1, o2;
            #pragma unroll
            for (int i = 0; i < 4; i++) {
                float e = expf(l4[i]);
                o1[i] = e4[i] * sqrtf(e) + m4[i];
                o2[i] = 1.f + l4[i] - m4[i] * m4[i] - e;
            }
            *(f32x4*)&out[grow * 512 + lane * 4]       = o1;
            *(f32x4*)&out[grow * 512 + 256 + lane * 4] = o2;
        }
    }
}

// ---------------------------------------------------------------------------
extern "C" void kernel_launch(void* const* d_in, const int* in_sizes, int n_in,
                              void* d_out, int out_size, void* d_ws, size_t ws_size,
                              hipStream_t stream) {
    const float* box  = (const float*)d_in[0];
    const float* eps  = (const float*)d_in[1];
    const float* Wbox = (const float*)d_in[2];
    const float* bbox = (const float*)d_in[3];
    const float* W1   = (const float*)d_in[4];
    const float* b1   = (const float*)d_in[5];
    const float* W2   = (const float*)d_in[6];
    const float* b2   = (const float*)d_in[7];
    const float* Ws1  = (const float*)d_in[8];
    const float* bs1  = (const float*)d_in[9];
    const float* Wmu  = (const float*)d_in[10];
    const float* bmu  = (const float*)d_in[11];
    const float* Wvar = (const float*)d_in[12];
    const float* bvar = (const float*)d_in[13];
    const int*   sem  = (const int*)d_in[14];
    const int*   nch  = (const int*)d_in[15];

    f16* wsh  = (f16*)d_ws;
    f16* xbuf = wsh + XBUF_OFF;

    kconv<<<XBUF_OFF / 256, 256, 0, stream>>>(W1, W2, Ws1, Wmu, Wvar, Wbox, wsh);
    k1<<<NPAR / 8, 256, 0, stream>>>(box, bbox, b1, sem, nch, wsh, xbuf);
    k2<<<NPAR / 32, 256, 0, stream>>>(xbuf, wsh, b2, bs1, bmu, bvar, eps, (float*)d_out);
}